// Round 4
// baseline (570.143 us; speedup 1.0000x reference)
//
#include <hip/hip_runtime.h>
#include <math.h>

#define BB 32
#define CC 768
#define HH 24
#define WWD 24
#define NSP 576     // spatial tokens
#define NT 577      // + CLS
#define EE 768
#define NH 8
#define HD 96

// ---------------- trig table: ct/st[n][i], n in 0..575, i in 0..47 ----------------
__global__ void ktrig(float* __restrict__ ct, float* __restrict__ st) {
    int idx = blockIdx.x * 256 + threadIdx.x;   // 576*48 = 27648 = 108*256
    int n = idx / 48, i = idx % 48;
    int r = n / WWD, c = n % WWD;
    float coord = (i < 24) ? (-1.f + 2.f * (float)r / 23.f)
                           : (-1.f + 2.f * (float)c / 23.f);
    float band = exp2f((float)(i % 24) * (3.0f / 23.0f));
    float e = coord * 3.14159265358979323846f * band;
    ct[idx] = cosf(e);
    st[idx] = sinf(e);
}

// ---------------- mean over spatial: mean[b*C+c] ----------------
__global__ void kmean(const float* __restrict__ x, float* __restrict__ mean) {
    int row = blockIdx.x * 4 + (threadIdx.x >> 6);   // b*C + c, 24576 rows
    int lane = threadIdx.x & 63;
    const float* p = x + (size_t)row * NSP;
    float s = 0.f;
    for (int k = lane; k < NSP; k += 64) s += p[k];
    for (int o = 32; o; o >>= 1) s += __shfl_xor(s, o);
    if (lane == 0) mean[row] = s * (1.0f / NSP);
}

// ---------------- CLS q/k: qcls[b][j], kcls[b][j] ----------------
// grid (6, 32) block 256: each wave handles 64 j serially, lanes over c
__global__ void kcls(const float* __restrict__ qkv_w, const float* __restrict__ qkv_b,
                     const float* __restrict__ mean,
                     float* __restrict__ qcls, float* __restrict__ kcls) {
    int b = blockIdx.y;
    int wave = threadIdx.x >> 6, lane = threadIdx.x & 63;
    const float* m = mean + b * CC;
    float mv[12];
#pragma unroll
    for (int k = 0; k < 12; k++) mv[k] = m[lane + 64 * k];
    int jbase = blockIdx.x * 256 + wave * 64;
    for (int jj = 0; jj < 64; jj++) {
        int j = jbase + jj;                   // 0..1535 (q rows then k rows)
        const float* wr = qkv_w + (size_t)j * CC;
        float s = 0.f;
#pragma unroll
        for (int k = 0; k < 12; k++) s += wr[lane + 64 * k] * mv[k];
        for (int o = 32; o; o >>= 1) s += __shfl_xor(s, o);
        if (lane == 0) {
            float v = s + qkv_b[j];
            if (j < EE) qcls[b * EE + j] = v;
            else        kcls[b * EE + (j - EE)] = v;
        }
    }
}

// ---------------- main GEMM: k = Wk@x[b] + bk, rope, dot with q_cls, atomic into sbuf ----------------
#define BM 128
#define BN 64
#define BK 32
// grid (54, 32) block 128. blockIdx.x = jt*9 + nt.
__global__ __launch_bounds__(128) void kgemm_score(
        const float* __restrict__ qkv_w, const float* __restrict__ qkv_b,
        const float* __restrict__ x,
        const float* __restrict__ ct, const float* __restrict__ st,
        const float* __restrict__ qcls, float* __restrict__ sbuf) {
    __shared__ float As[BK][BM + 4];   // transposed Wk tile, +4 pad keeps rows 16B-aligned
    __shared__ float Bs[BK][BN];
    int b = blockIdx.y;
    int jt = blockIdx.x / 9, nt = blockIdx.x % 9;
    int j0 = jt * BM, n0 = nt * BN;
    int tid = threadIdx.x;
    int tx = tid & 7, ty = tid >> 3;          // 8x8 outputs per thread: rows ty*8.., cols tx*8..
    const float* Wk = qkv_w + (size_t)EE * CC;     // k rows start at 768
    const float* xb = x + (size_t)b * CC * NSP;

    float acc[8][8];
#pragma unroll
    for (int i = 0; i < 8; i++)
#pragma unroll
        for (int u = 0; u < 8; u++) acc[i][u] = 0.f;

    int ac4 = tid & 7, ar = tid >> 3;     // A loader: col-group 0..7, row 0..15 (+16*i)
    int bn4 = tid & 15, bc = tid >> 4;    // B loader: n-group 0..15, row 0..7 (+8*i)

    for (int c0 = 0; c0 < CC; c0 += BK) {
#pragma unroll
        for (int i = 0; i < 8; i++) {
            int r = ar + 16 * i;
            float4 v = *(const float4*)(Wk + (size_t)(j0 + r) * CC + c0 + ac4 * 4);
            As[ac4 * 4 + 0][r] = v.x;
            As[ac4 * 4 + 1][r] = v.y;
            As[ac4 * 4 + 2][r] = v.z;
            As[ac4 * 4 + 3][r] = v.w;
        }
#pragma unroll
        for (int i = 0; i < 4; i++) {
            int r = bc + 8 * i;
            *(float4*)(&Bs[r][bn4 * 4]) =
                *(const float4*)(xb + (size_t)(c0 + r) * NSP + n0 + bn4 * 4);
        }
        __syncthreads();
#pragma unroll 2
        for (int kk = 0; kk < BK; kk++) {
            float4 a0 = *(const float4*)&As[kk][ty * 8];
            float4 a1 = *(const float4*)&As[kk][ty * 8 + 4];
            float4 b0 = *(const float4*)&Bs[kk][tx * 8];
            float4 b1 = *(const float4*)&Bs[kk][tx * 8 + 4];
            float a[8] = {a0.x, a0.y, a0.z, a0.w, a1.x, a1.y, a1.z, a1.w};
            float bv[8] = {b0.x, b0.y, b0.z, b0.w, b1.x, b1.y, b1.z, b1.w};
#pragma unroll
            for (int i = 0; i < 8; i++)
#pragma unroll
                for (int u = 0; u < 8; u++) acc[i][u] += a[i] * bv[u];
        }
        __syncthreads();
    }

    // epilogue: bias + rope + q-dot + atomic score accumulate
    int h = (j0 + ty * 8) / HD;    // 8 consecutive rows never straddle a head (8 | 96)
    float qv[8], bias[8];
#pragma unroll
    for (int i = 0; i < 8; i++) {
        int j = j0 + ty * 8 + i;
        bias[i] = qkv_b[EE + j];
        qv[i] = qcls[b * EE + j];
    }
    float* sdst = sbuf + (size_t)(b * NH + h) * NT;
#pragma unroll
    for (int u = 0; u < 8; u++) {
        int n = n0 + tx * 8 + u;          // spatial 0..575 -> token n+1
        float s = 0.f;
#pragma unroll
        for (int pr = 0; pr < 4; pr++) {
            int j = j0 + ty * 8 + pr * 2;
            int fi = (j % HD) >> 1;       // freq index 0..47
            float cv = ct[n * 48 + fi], sv = st[n * 48 + fi];
            float e0 = acc[pr * 2][u] + bias[pr * 2];
            float e1 = acc[pr * 2 + 1][u] + bias[pr * 2 + 1];
            float r0 = e0 * cv - e1 * sv;
            float r1 = e1 * cv + e0 * sv;
            s += qv[pr * 2] * r0 + qv[pr * 2 + 1] * r1;
        }
        unsafeAtomicAdd(sdst + n + 1, s);
    }
}

// ---------------- softmax over 577 scores -> p ----------------
__global__ void ksoftmax(const float* __restrict__ sbuf, const float* __restrict__ qcls,
                         const float* __restrict__ kcls, float* __restrict__ p) {
    int bh = blockIdx.x, b = bh >> 3, h = bh & 7;
    int tid = threadIdx.x;
    __shared__ float sm[NT];
    __shared__ float red[4];
    // CLS score
    float c0 = 0.f;
    if (tid < HD) c0 = qcls[b * EE + h * HD + tid] * kcls[b * EE + h * HD + tid];
    for (int o = 32; o; o >>= 1) c0 += __shfl_xor(c0, o);
    if ((tid & 63) == 0) red[tid >> 6] = c0;
    __syncthreads();
    float s0 = red[0] + red[1] + red[2] + red[3];
    const float scale = 0.10206207261596575f;   // 96^-0.5
    for (int n = tid; n < NT; n += 256)
        sm[n] = (n == 0 ? s0 : sbuf[(size_t)bh * NT + n]) * scale;
    __syncthreads();
    float m = -1e30f;
    for (int n = tid; n < NT; n += 256) m = fmaxf(m, sm[n]);
    for (int o = 32; o; o >>= 1) m = fmaxf(m, __shfl_xor(m, o));
    __syncthreads();
    if ((tid & 63) == 0) red[tid >> 6] = m;
    __syncthreads();
    m = fmaxf(fmaxf(red[0], red[1]), fmaxf(red[2], red[3]));
    float lsum = 0.f;
    for (int n = tid; n < NT; n += 256) {
        float e = expf(sm[n] - m);
        sm[n] = e;
        lsum += e;
    }
    for (int o = 32; o; o >>= 1) lsum += __shfl_xor(lsum, o);
    __syncthreads();
    if ((tid & 63) == 0) red[tid >> 6] = lsum;
    __syncthreads();
    float inv = 1.0f / (red[0] + red[1] + red[2] + red[3]);
    for (int n = tid; n < NT; n += 256) p[(size_t)bh * NT + n] = sm[n] * inv;
}

// ---------------- weighted token sum: w[b][h][c] = sum_n p[n] t[n][c] ----------------
// grid (192, 32) block 256; each wave owns one c row, all 8 heads at once
__global__ void kwsum(const float* __restrict__ x, const float* __restrict__ mean,
                      const float* __restrict__ p, float* __restrict__ w) {
    __shared__ float ps[NH][NT];   // 18.5 KB
    int b = blockIdx.y;
    int tid = threadIdx.x;
    for (int i = tid; i < NH * NT; i += 256)
        ps[i / NT][i % NT] = p[(size_t)b * NH * NT + i];
    __syncthreads();
    int wave = tid >> 6, lane = tid & 63;
    int c = blockIdx.x * 4 + wave;
    const float* xr = x + ((size_t)b * CC + c) * NSP;
    float acc[NH];
#pragma unroll
    for (int h = 0; h < NH; h++) acc[h] = 0.f;
    for (int n = lane; n < NSP; n += 64) {
        float xv = xr[n];
#pragma unroll
        for (int h = 0; h < NH; h++) acc[h] += ps[h][n + 1] * xv;
    }
#pragma unroll
    for (int h = 0; h < NH; h++)
        for (int o = 32; o; o >>= 1) acc[h] += __shfl_xor(acc[h], o);
    if (lane == 0) {
        float mv = mean[b * CC + c];
#pragma unroll
        for (int h = 0; h < NH; h++)
            w[((size_t)(b * NH + h)) * CC + c] = acc[h] + ps[h][0] * mv;
    }
}

// ---------------- o[b][j] = Wv[j,:] . w[b][j/96] + bv[j] ----------------
__global__ void kvproj(const float* __restrict__ qkv_w, const float* __restrict__ qkv_b,
                       const float* __restrict__ w, float* __restrict__ o) {
    int b = blockIdx.y;
    int wave = threadIdx.x >> 6, lane = threadIdx.x & 63;
    int jbase = blockIdx.x * 256 + wave * 64;
    for (int jj = 0; jj < 64; jj++) {
        int j = jbase + jj;
        int h = j / HD;
        const float* wr = qkv_w + (size_t)(2 * EE + j) * CC;
        const float* wv = w + (size_t)(b * NH + h) * CC;
        float s = 0.f;
#pragma unroll
        for (int k = 0; k < 12; k++) s += wr[lane + 64 * k] * wv[lane + 64 * k];
        for (int oo = 32; oo; oo >>= 1) s += __shfl_xor(s, oo);
        if (lane == 0) o[b * EE + j] = s + qkv_b[2 * EE + j];
    }
}

// ---------------- out[b][e] = proj_w[e,:] . o[b] + proj_b[e] ----------------
__global__ void kproj(const float* __restrict__ proj_w, const float* __restrict__ proj_b,
                      const float* __restrict__ o, float* __restrict__ out) {
    int b = blockIdx.y;
    int wave = threadIdx.x >> 6, lane = threadIdx.x & 63;
    int jbase = blockIdx.x * 256 + wave * 64;
    const float* ob = o + b * EE;
    float ov[12];
#pragma unroll
    for (int k = 0; k < 12; k++) ov[k] = ob[lane + 64 * k];
    for (int jj = 0; jj < 64; jj++) {
        int j = jbase + jj;
        const float* wr = proj_w + (size_t)j * CC;
        float s = 0.f;
#pragma unroll
        for (int k = 0; k < 12; k++) s += wr[lane + 64 * k] * ov[k];
        for (int oo = 32; oo; oo >>= 1) s += __shfl_xor(s, oo);
        if (lane == 0) out[b * EE + j] = s + proj_b[j];
    }
}

extern "C" void kernel_launch(void* const* d_in, const int* in_sizes, int n_in,
                              void* d_out, int out_size, void* d_ws, size_t ws_size,
                              hipStream_t stream) {
    (void)in_sizes; (void)n_in; (void)out_size; (void)ws_size;
    const float* x      = (const float*)d_in[0];
    const float* qkv_w  = (const float*)d_in[1];
    const float* qkv_b  = (const float*)d_in[2];
    const float* proj_w = (const float*)d_in[3];
    const float* proj_b = (const float*)d_in[4];
    float* out = (float*)d_out;
    float* ws = (float*)d_ws;

    // NOTE: these local names must NOT shadow kernel symbols (round-3 compile bug:
    // a local `kcls` pointer shadowed the __global__ kcls).
    float* sbuf = ws;                 // 32*8*577   = 147712
    float* pbuf = ws + 147712;        // 147712
    float* mbuf = ws + 295424;        // 24576
    float* qcb  = ws + 320000;        // 24576
    float* kcb  = ws + 344576;        // 24576
    float* ctb  = ws + 369152;        // 27648
    float* stb  = ws + 396800;        // 27648
    float* wbuf = ws + 424448;        // 196608
    float* obuf = ws + 621056;        // 24576   (total 645632 floats ~ 2.6 MB)

    (void)hipMemsetAsync(sbuf, 0, 147712 * sizeof(float), stream);
    ktrig<<<108, 256, 0, stream>>>(ctb, stb);
    kmean<<<6144, 256, 0, stream>>>(x, mbuf);
    kcls<<<dim3(6, 32), 256, 0, stream>>>(qkv_w, qkv_b, mbuf, qcb, kcb);
    kgemm_score<<<dim3(54, 32), 128, 0, stream>>>(qkv_w, qkv_b, x, ctb, stb, qcb, sbuf);
    ksoftmax<<<256, 256, 0, stream>>>(sbuf, qcb, kcb, pbuf);
    kwsum<<<dim3(192, 32), 256, 0, stream>>>(x, mbuf, pbuf, wbuf);
    kvproj<<<dim3(3, 32), 256, 0, stream>>>(qkv_w, qkv_b, wbuf, obuf);
    kproj<<<dim3(3, 32), 256, 0, stream>>>(proj_w, proj_b, obuf, out);
}

// Round 5
// 436.538 us; speedup vs baseline: 1.3061x; 1.3061x over previous
//
#include <hip/hip_runtime.h>
#include <math.h>

#define CC 768
#define HH 24
#define WWD 24
#define NSP 576     // spatial tokens
#define NT 577      // + CLS
#define EE 768
#define NH 8
#define HD 96

typedef float f32x4 __attribute__((ext_vector_type(4)));
typedef __bf16 bf16x8 __attribute__((ext_vector_type(8)));
typedef __bf16 bf16x4 __attribute__((ext_vector_type(4)));

// ---------------- trig table: ct/st[n][i], n in 0..575, i in 0..47 ----------------
__global__ void ktrig(float* __restrict__ ct, float* __restrict__ st) {
    int idx = blockIdx.x * 256 + threadIdx.x;   // 576*48 = 27648 = 108*256
    int n = idx / 48, i = idx % 48;
    int r = n / WWD, c = n % WWD;
    float coord = (i < 24) ? (-1.f + 2.f * (float)r / 23.f)
                           : (-1.f + 2.f * (float)c / 23.f);
    float band = exp2f((float)(i % 24) * (3.0f / 23.0f));
    float e = coord * 3.14159265358979323846f * band;
    ct[idx] = cosf(e);
    st[idx] = sinf(e);
}

// ---------------- mean over spatial: mean[b*C+c] ----------------
__global__ void kmean(const float* __restrict__ x, float* __restrict__ mean) {
    int row = blockIdx.x * 4 + (threadIdx.x >> 6);   // b*C + c, 24576 rows
    int lane = threadIdx.x & 63;
    const float* p = x + (size_t)row * NSP;
    float s = 0.f;
    for (int k = lane; k < NSP; k += 64) s += p[k];
    for (int o = 32; o; o >>= 1) s += __shfl_xor(s, o);
    if (lane == 0) mean[row] = s * (1.0f / NSP);
}

// ---------------- CLS q/k, batch-amortized: weights read once per 16 batches ----------
// grid (96, 2) block 256: block = 16 j-rows x 16 batches; means staged in LDS (48 KB)
__global__ __launch_bounds__(256) void kcls(const float* __restrict__ qkv_w,
                                            const float* __restrict__ qkv_b,
                                            const float* __restrict__ mean,
                                            float* __restrict__ qcls, float* __restrict__ kcls) {
    __shared__ float mlds[16][768];
    int bg = blockIdx.y;
    int tid = threadIdx.x;
#pragma unroll
    for (int i = 0; i < 12; i++) {
        int f4 = i * 256 + tid;                 // 0..3071
        int row = f4 / 192, col = (f4 % 192) * 4;
        *(float4*)&mlds[row][col] = *(const float4*)&mean[(size_t)(bg * 16 + row) * CC + col];
    }
    __syncthreads();
    int wid = tid >> 6, lane = tid & 63;
    for (int jj = 0; jj < 4; jj++) {
        int j = blockIdx.x * 16 + wid * 4 + jj;   // 0..1535 (q rows then k rows)
        const float* wr = qkv_w + (size_t)j * CC;
        float wv[12];
#pragma unroll
        for (int k = 0; k < 12; k++) wv[k] = wr[lane + 64 * k];
        float bias = qkv_b[j];
        for (int bb = 0; bb < 16; bb++) {
            float s = 0.f;
#pragma unroll
            for (int k = 0; k < 12; k++) s += wv[k] * mlds[bb][lane + 64 * k];
            for (int o = 32; o; o >>= 1) s += __shfl_xor(s, o);
            if (lane == 0) {
                int b = bg * 16 + bb;
                float v = s + bias;
                if (j < EE) qcls[(size_t)b * EE + j] = v;
                else        kcls[(size_t)b * EE + (j - EE)] = v;
            }
        }
    }
}

// ---------------- main GEMM (split-bf16 MFMA): k = Wk@x[b]+bk, rope, q-dot, atomic ----------
// Split each fp32 into hi+lo bf16; D = Ahi*Bhi + Ahi*Blo + Alo*Bhi (lo*lo term ~2^-18, dropped).
// Tile 192j x 192n, BK=32. 512 thr = 8 waves (2m x 4n); wave = 96j x 48n = 6x3 frags 16x16x32.
#define BMJ 192
#define BNN 192
#define BKC 32
#define LDK 40   // padded row stride (elems): b128 frag reads 16B-aligned + bank-balanced

__global__ __launch_bounds__(512, 2) void kgemm_score(
        const float* __restrict__ qkv_w, const float* __restrict__ qkv_b,
        const float* __restrict__ x,
        const float* __restrict__ ct, const float* __restrict__ st,
        const float* __restrict__ qcls, float* __restrict__ sbuf) {
    __shared__ __bf16 Ahi[BMJ * LDK], Alo[BMJ * LDK], Bhi[BNN * LDK], Blo[BNN * LDK];
    int b = blockIdx.y;
    int jt = blockIdx.x / 3, nt = blockIdx.x % 3;
    int j0 = jt * BMJ, n0 = nt * BNN;
    int tid = threadIdx.x;
    int wid = tid >> 6, lane = tid & 63;
    int wm = wid >> 2, wn = wid & 3;
    const float* Wk = qkv_w + (size_t)EE * CC;
    const float* xb = x + (size_t)b * CC * NSP;

    f32x4 acc[6][3];
#pragma unroll
    for (int i = 0; i < 6; i++)
#pragma unroll
        for (int u = 0; u < 3; u++) acc[i][u] = (f32x4){0.f, 0.f, 0.f, 0.f};

    int isA = (wid < 4);
    int u8 = tid & 255;
    // A loader: f4id = i*256+u8 -> row r = (u8>>3)+32i, k-quad k4 = u8&7
    // B loader: c = u8>>3 (0..31), n4 = (u8&7)+8i
    const float* gA = Wk + (size_t)(j0 + (u8 >> 3)) * CC + (u8 & 7) * 4;
    const float* gB = xb + (size_t)(u8 >> 3) * NSP + n0 + (u8 & 7) * 4;

    float4 ga[6];
    // prologue: load tile for c0 = 0
    if (isA) {
#pragma unroll
        for (int i = 0; i < 6; i++) ga[i] = *(const float4*)(gA + (size_t)i * 32 * CC);
    } else {
#pragma unroll
        for (int i = 0; i < 6; i++) ga[i] = *(const float4*)(gB + i * 32);
    }

    for (int s = 0; s < 24; ++s) {
        // ---- stage ga -> LDS (convert to hi/lo bf16) ----
        if (isA) {
            int r0 = u8 >> 3, k4 = (u8 & 7) * 4;
#pragma unroll
            for (int i = 0; i < 6; i++) {
                float vv[4] = {ga[i].x, ga[i].y, ga[i].z, ga[i].w};
                bf16x4 h, l;
#pragma unroll
                for (int ii = 0; ii < 4; ii++) {
                    __bf16 hb = (__bf16)vv[ii];
                    h[ii] = hb;
                    l[ii] = (__bf16)(vv[ii] - (float)hb);
                }
                int r = r0 + 32 * i;
                *(bf16x4*)&Ahi[r * LDK + k4] = h;
                *(bf16x4*)&Alo[r * LDK + k4] = l;
            }
        } else {
            int c = u8 >> 3, nb = (u8 & 7) * 4;
#pragma unroll
            for (int i = 0; i < 6; i++) {
                float vv[4] = {ga[i].x, ga[i].y, ga[i].z, ga[i].w};
#pragma unroll
                for (int ii = 0; ii < 4; ii++) {
                    int n = nb + 32 * i + ii;
                    __bf16 hb = (__bf16)vv[ii];
                    Bhi[n * LDK + c] = hb;
                    Blo[n * LDK + c] = (__bf16)(vv[ii] - (float)hb);
                }
            }
        }
        __syncthreads();
        // ---- issue next tile's global loads (in flight during MFMA) ----
        if (s < 23) {
            int c0 = (s + 1) * BKC;
            if (isA) {
#pragma unroll
                for (int i = 0; i < 6; i++) ga[i] = *(const float4*)(gA + (size_t)i * 32 * CC + c0);
            } else {
#pragma unroll
                for (int i = 0; i < 6; i++) ga[i] = *(const float4*)(gB + (size_t)c0 * NSP + i * 32);
            }
        }
        // ---- compute: read frags, 54 MFMA ----
        {
            int ko = (lane >> 4) << 3;
            int rB = wn * 48 + (lane & 15);
            bf16x8 pbh[3], pbl[3];
#pragma unroll
            for (int ni = 0; ni < 3; ni++) {
                pbh[ni] = *(const bf16x8*)&Bhi[(rB + ni * 16) * LDK + ko];
                pbl[ni] = *(const bf16x8*)&Blo[(rB + ni * 16) * LDK + ko];
            }
            int rA = wm * 96 + (lane & 15);
#pragma unroll
            for (int mi = 0; mi < 6; mi++) {
                bf16x8 ah = *(const bf16x8*)&Ahi[(rA + mi * 16) * LDK + ko];
                bf16x8 al = *(const bf16x8*)&Alo[(rA + mi * 16) * LDK + ko];
#pragma unroll
                for (int ni = 0; ni < 3; ni++) {
                    acc[mi][ni] = __builtin_amdgcn_mfma_f32_16x16x32_bf16(ah, pbh[ni], acc[mi][ni], 0, 0, 0);
                    acc[mi][ni] = __builtin_amdgcn_mfma_f32_16x16x32_bf16(ah, pbl[ni], acc[mi][ni], 0, 0, 0);
                    acc[mi][ni] = __builtin_amdgcn_mfma_f32_16x16x32_bf16(al, pbh[ni], acc[mi][ni], 0, 0, 0);
                }
            }
        }
        __syncthreads();
    }

    // ---- epilogue: bias + rope + q-dot + reduce + atomic ----
    // C/D layout: col = lane&15 (n), row = (lane>>4)*4 + reg (j). 4 consecutive j per lane.
#pragma unroll
    for (int mi = 0; mi < 6; mi++) {
        int jf = j0 + wm * 96 + mi * 16;          // 16-aligned, within one head (16 | 96)
        int h = jf / HD;
        float* sdst = sbuf + (size_t)(b * NH + h) * NT;
        int jl = jf + ((lane >> 4) << 2);         // this lane's first j (mult of 4, even)
        float4 qv4 = *(const float4*)&qcls[(size_t)b * EE + jl];
        float4 bi4 = *(const float4*)&qkv_b[EE + jl];
        int fi = (jl % HD) >> 1;                  // even
#pragma unroll
        for (int ni = 0; ni < 3; ni++) {
            int n = n0 + wn * 48 + ni * 16 + (lane & 15);
            float2 cv = *(const float2*)&ct[n * 48 + fi];
            float2 sv = *(const float2*)&st[n * 48 + fi];
            f32x4 a = acc[mi][ni];
            float e0 = a[0] + bi4.x, e1 = a[1] + bi4.y;
            float e2 = a[2] + bi4.z, e3 = a[3] + bi4.w;
            float s = qv4.x * (e0 * cv.x - e1 * sv.x) + qv4.y * (e1 * cv.x + e0 * sv.x)
                    + qv4.z * (e2 * cv.y - e3 * sv.y) + qv4.w * (e3 * cv.y + e2 * sv.y);
            s += __shfl_xor(s, 16);
            s += __shfl_xor(s, 32);
            if (lane < 16) unsafeAtomicAdd(sdst + n + 1, s);
        }
    }
}

// ---------------- softmax over 577 scores -> p ----------------
__global__ void ksoftmax(const float* __restrict__ sbuf, const float* __restrict__ qcls,
                         const float* __restrict__ kcls, float* __restrict__ p) {
    int bh = blockIdx.x, b = bh >> 3, h = bh & 7;
    int tid = threadIdx.x;
    __shared__ float sm[NT];
    __shared__ float red[4];
    float c0 = 0.f;
    if (tid < HD) c0 = qcls[b * EE + h * HD + tid] * kcls[b * EE + h * HD + tid];
    for (int o = 32; o; o >>= 1) c0 += __shfl_xor(c0, o);
    if ((tid & 63) == 0) red[tid >> 6] = c0;
    __syncthreads();
    float s0 = red[0] + red[1] + red[2] + red[3];
    const float scale = 0.10206207261596575f;   // 96^-0.5
    for (int n = tid; n < NT; n += 256)
        sm[n] = (n == 0 ? s0 : sbuf[(size_t)bh * NT + n]) * scale;
    __syncthreads();
    float m = -1e30f;
    for (int n = tid; n < NT; n += 256) m = fmaxf(m, sm[n]);
    for (int o = 32; o; o >>= 1) m = fmaxf(m, __shfl_xor(m, o));
    __syncthreads();
    if ((tid & 63) == 0) red[tid >> 6] = m;
    __syncthreads();
    m = fmaxf(fmaxf(red[0], red[1]), fmaxf(red[2], red[3]));
    float lsum = 0.f;
    for (int n = tid; n < NT; n += 256) {
        float e = expf(sm[n] - m);
        sm[n] = e;
        lsum += e;
    }
    for (int o = 32; o; o >>= 1) lsum += __shfl_xor(lsum, o);
    __syncthreads();
    if ((tid & 63) == 0) red[tid >> 6] = lsum;
    __syncthreads();
    float inv = 1.0f / (red[0] + red[1] + red[2] + red[3]);
    for (int n = tid; n < NT; n += 256) p[(size_t)bh * NT + n] = sm[n] * inv;
}

// ---------------- weighted token sum: w[b][h][c] = sum_n p[n] t[n][c] ----------------
__global__ void kwsum(const float* __restrict__ x, const float* __restrict__ mean,
                      const float* __restrict__ p, float* __restrict__ w) {
    __shared__ float ps[NH][NT];
    int b = blockIdx.y;
    int tid = threadIdx.x;
    for (int i = tid; i < NH * NT; i += 256)
        ps[i / NT][i % NT] = p[(size_t)b * NH * NT + i];
    __syncthreads();
    int wave = tid >> 6, lane = tid & 63;
    int c = blockIdx.x * 4 + wave;
    const float* xr = x + ((size_t)b * CC + c) * NSP;
    float acc[NH];
#pragma unroll
    for (int h = 0; h < NH; h++) acc[h] = 0.f;
    for (int n = lane; n < NSP; n += 64) {
        float xv = xr[n];
#pragma unroll
        for (int h = 0; h < NH; h++) acc[h] += ps[h][n + 1] * xv;
    }
#pragma unroll
    for (int h = 0; h < NH; h++)
        for (int o = 32; o; o >>= 1) acc[h] += __shfl_xor(acc[h], o);
    if (lane == 0) {
        float mv = mean[b * CC + c];
#pragma unroll
        for (int h = 0; h < NH; h++)
            w[((size_t)(b * NH + h)) * CC + c] = acc[h] + ps[h][0] * mv;
    }
}

// ---------------- o[b][j] = Wv[j,:] . w[b][j/96] + bv[j] ----------------
__global__ void kvproj(const float* __restrict__ qkv_w, const float* __restrict__ qkv_b,
                       const float* __restrict__ w, float* __restrict__ o) {
    int b = blockIdx.y;
    int wave = threadIdx.x >> 6, lane = threadIdx.x & 63;
    int jbase = blockIdx.x * 256 + wave * 64;
    for (int jj = 0; jj < 64; jj++) {
        int j = jbase + jj;
        int h = j / HD;
        const float* wr = qkv_w + (size_t)(2 * EE + j) * CC;
        const float* wv = w + (size_t)(b * NH + h) * CC;
        float s = 0.f;
#pragma unroll
        for (int k = 0; k < 12; k++) s += wr[lane + 64 * k] * wv[lane + 64 * k];
        for (int oo = 32; oo; oo >>= 1) s += __shfl_xor(s, oo);
        if (lane == 0) o[b * EE + j] = s + qkv_b[2 * EE + j];
    }
}

// ---------------- out[b][e] = proj_w[e,:] . o[b] + proj_b[e] ----------------
__global__ void kproj(const float* __restrict__ proj_w, const float* __restrict__ proj_b,
                      const float* __restrict__ o, float* __restrict__ out) {
    int b = blockIdx.y;
    int wave = threadIdx.x >> 6, lane = threadIdx.x & 63;
    int jbase = blockIdx.x * 256 + wave * 64;
    const float* ob = o + b * EE;
    float ov[12];
#pragma unroll
    for (int k = 0; k < 12; k++) ov[k] = ob[lane + 64 * k];
    for (int jj = 0; jj < 64; jj++) {
        int j = jbase + jj;
        const float* wr = proj_w + (size_t)j * CC;
        float s = 0.f;
#pragma unroll
        for (int k = 0; k < 12; k++) s += wr[lane + 64 * k] * ov[k];
        for (int oo = 32; oo; oo >>= 1) s += __shfl_xor(s, oo);
        if (lane == 0) out[b * EE + j] = s + proj_b[j];
    }
}

extern "C" void kernel_launch(void* const* d_in, const int* in_sizes, int n_in,
                              void* d_out, int out_size, void* d_ws, size_t ws_size,
                              hipStream_t stream) {
    (void)in_sizes; (void)n_in; (void)out_size; (void)ws_size;
    const float* x      = (const float*)d_in[0];
    const float* qkv_w  = (const float*)d_in[1];
    const float* qkv_b  = (const float*)d_in[2];
    const float* proj_w = (const float*)d_in[3];
    const float* proj_b = (const float*)d_in[4];
    float* out = (float*)d_out;
    float* ws = (float*)d_ws;

    // NOTE: local names must NOT shadow kernel symbols (round-3 compile bug).
    float* sbuf = ws;                 // 32*8*577   = 147712
    float* pbuf = ws + 147712;        // 147712
    float* mbuf = ws + 295424;        // 24576
    float* qcb  = ws + 320000;        // 24576
    float* kcb  = ws + 344576;        // 24576
    float* ctb  = ws + 369152;        // 27648
    float* stb  = ws + 396800;        // 27648
    float* wbuf = ws + 424448;        // 196608
    float* obuf = ws + 621056;        // 24576   (total 645632 floats ~ 2.6 MB)

    (void)hipMemsetAsync(sbuf, 0, 147712 * sizeof(float), stream);
    ktrig<<<108, 256, 0, stream>>>(ctb, stb);
    kmean<<<6144, 256, 0, stream>>>(x, mbuf);
    kcls<<<dim3(96, 2), 256, 0, stream>>>(qkv_w, qkv_b, mbuf, qcb, kcb);
    kgemm_score<<<dim3(12, 32), 512, 0, stream>>>(qkv_w, qkv_b, x, ctb, stb, qcb, sbuf);
    ksoftmax<<<256, 256, 0, stream>>>(sbuf, qcb, kcb, pbuf);
    kwsum<<<dim3(192, 32), 256, 0, stream>>>(x, mbuf, pbuf, wbuf);
    kvproj<<<dim3(3, 32), 256, 0, stream>>>(qkv_w, qkv_b, wbuf, obuf);
    kproj<<<dim3(3, 32), 256, 0, stream>>>(proj_w, proj_b, obuf, out);
}

// Round 6
// 351.435 us; speedup vs baseline: 1.6223x; 1.2422x over previous
//
#include <hip/hip_runtime.h>
#include <math.h>

#define CC 768
#define WWD 24
#define NSP 576     // spatial tokens
#define NT 577      // + CLS
#define EE 768
#define NH 8
#define HD 96

typedef float f32x4 __attribute__((ext_vector_type(4)));
typedef __bf16 bf16x8 __attribute__((ext_vector_type(8)));
typedef __bf16 bf16x4 __attribute__((ext_vector_type(4)));

__device__ __forceinline__ void gload16(const void* g, void* l) {
    __builtin_amdgcn_global_load_lds((const __attribute__((address_space(1))) void*)g,
                                     (__attribute__((address_space(3))) void*)l, 16, 0, 0);
}

// ---------------- trig table: ct/st[n][i], n in 0..575, i in 0..47 ----------------
__global__ void ktrig(float* __restrict__ ct, float* __restrict__ st) {
    int idx = blockIdx.x * 256 + threadIdx.x;   // 27648 = 108*256
    int n = idx / 48, i = idx % 48;
    int r = n / WWD, c = n % WWD;
    float coord = (i < 24) ? (-1.f + 2.f * (float)r / 23.f)
                           : (-1.f + 2.f * (float)c / 23.f);
    float band = exp2f((float)(i % 24) * (3.0f / 23.0f));
    float e = coord * 3.14159265358979323846f * band;
    ct[idx] = cosf(e);
    st[idx] = sinf(e);
}

// ---------------- convert Wk (fp32) -> Whi/Wlo bf16, row-major [768][768] ----------------
__global__ void kconvw(const float* __restrict__ qkv_w,
                       __bf16* __restrict__ Whi, __bf16* __restrict__ Wlo) {
    size_t i = ((size_t)blockIdx.x * 256 + threadIdx.x) * 4;   // 576 blocks
    const float* Wk = qkv_w + (size_t)EE * CC;
    float4 v = *(const float4*)&Wk[i];
    float vv[4] = {v.x, v.y, v.z, v.w};
    bf16x4 h, l;
#pragma unroll
    for (int k = 0; k < 4; k++) {
        __bf16 hb = (__bf16)vv[k];
        h[k] = hb;
        l[k] = (__bf16)(vv[k] - (float)hb);
    }
    *(bf16x4*)&Whi[i] = h;
    *(bf16x4*)&Wlo[i] = l;
}

// ---------------- transpose+convert x[b] [C][N] f32 -> xt_hi/lo [b][N][C] bf16; fused mean ----
// grid (12, 9, 32) block 256: 64c x 64n tiles
__global__ __launch_bounds__(256) void kconvx(const float* __restrict__ x,
                                              float* __restrict__ msum,
                                              __bf16* __restrict__ xth,
                                              __bf16* __restrict__ xtl) {
    __shared__ float t[64][65];   // pad 65: write banks 2-way, read banks (c+n)%32 2-way
    int b = blockIdx.z, ct0 = blockIdx.x * 64, nt0 = blockIdx.y * 64;
    int tid = threadIdx.x, lane = tid & 63;
#pragma unroll
    for (int it = 0; it < 4; ++it) {
        int cr = it * 16 + (tid >> 4);
        int ng = (tid & 15) * 4;
        float4 v = *(const float4*)&x[((size_t)b * CC + ct0 + cr) * NSP + nt0 + ng];
        t[cr][ng] = v.x; t[cr][ng + 1] = v.y; t[cr][ng + 2] = v.z; t[cr][ng + 3] = v.w;
        float ps = v.x + v.y + v.z + v.w;             // fused mean partial (over this n-tile)
        ps += __shfl_xor(ps, 1); ps += __shfl_xor(ps, 2);
        ps += __shfl_xor(ps, 4); ps += __shfl_xor(ps, 8);
        if ((lane & 15) == 0) unsafeAtomicAdd(&msum[(size_t)b * CC + ct0 + cr], ps);
    }
    __syncthreads();
#pragma unroll
    for (int it = 0; it < 2; ++it) {
        int nr = it * 32 + (tid >> 3);
        int cg = (tid & 7) * 8;
        float v[8];
#pragma unroll
        for (int k = 0; k < 8; k++) v[k] = t[cg + k][nr];
        bf16x8 h, l;
#pragma unroll
        for (int k = 0; k < 8; k++) {
            __bf16 hb = (__bf16)v[k];
            h[k] = hb;
            l[k] = (__bf16)(v[k] - (float)hb);
        }
        size_t o = ((size_t)b * NSP + nt0 + nr) * CC + ct0 + cg;
        *(bf16x8*)&xth[o] = h;
        *(bf16x8*)&xtl[o] = l;
    }
}

// ---------------- CLS q/k from raw mean sums (scale 1/576 applied post-dot) ----------------
// grid (96, 2) block 256
__global__ __launch_bounds__(256) void kcls(const float* __restrict__ qkv_w,
                                            const float* __restrict__ qkv_b,
                                            const float* __restrict__ msum,
                                            float* __restrict__ qcls, float* __restrict__ kcls) {
    __shared__ float mlds[16][768];
    int bg = blockIdx.y;
    int tid = threadIdx.x;
#pragma unroll
    for (int i = 0; i < 12; i++) {
        int f4 = i * 256 + tid;
        int row = f4 / 192, col = (f4 % 192) * 4;
        *(float4*)&mlds[row][col] = *(const float4*)&msum[(size_t)(bg * 16 + row) * CC + col];
    }
    __syncthreads();
    int wid = tid >> 6, lane = tid & 63;
    for (int jj = 0; jj < 4; jj++) {
        int j = blockIdx.x * 16 + wid * 4 + jj;   // 0..1535 (q rows then k rows)
        const float* wr = qkv_w + (size_t)j * CC;
        float wv[12];
#pragma unroll
        for (int k = 0; k < 12; k++) wv[k] = wr[lane + 64 * k];
        float bias = qkv_b[j];
        for (int bb = 0; bb < 16; bb++) {
            float s = 0.f;
#pragma unroll
            for (int k = 0; k < 12; k++) s += wv[k] * mlds[bb][lane + 64 * k];
            for (int o = 32; o; o >>= 1) s += __shfl_xor(s, o);
            if (lane == 0) {
                int b = bg * 16 + bb;
                float v = s * (1.0f / 576.0f) + bias;
                if (j < EE) qcls[(size_t)b * EE + j] = v;
                else        kcls[(size_t)b * EE + (j - EE)] = v;
            }
        }
    }
}

// ---------------- main GEMM: split-bf16 MFMA, global_load_lds staging, K-split=2 ----------
// BM=256 j, BN=128 n, BK=32. 512 thr = 8 waves (4m x 2n), wave 64x64 = 4x4 frags 16x16x32.
// XOR swizzle on 16B quads: q ^= (r>>1)&3, baked into global source AND ds_read addr.
// grid 960: id -> xcd=id&7, b=bq*8+xcd (batch clusters per XCD for xt L2 reuse).
__global__ __launch_bounds__(512, 4) void kgemm_score(
        const __bf16* __restrict__ Whi, const __bf16* __restrict__ Wlo,
        const __bf16* __restrict__ xth, const __bf16* __restrict__ xtl,
        const float* __restrict__ qkv_b, const float* __restrict__ ct,
        const float* __restrict__ st, const float* __restrict__ qcls,
        float* __restrict__ sbuf) {
    __shared__ __bf16 Ah[256 * 32], Al[256 * 32], Bh[128 * 32], Bl[128 * 32];  // 48 KB
    int id = blockIdx.x;
    int xcd = id & 7, within = id >> 3;
    int bq = within / 30, t = within % 30;
    int b = bq * 8 + xcd;
    int jt = t / 10, r2 = t % 10, nt = r2 >> 1, ks = r2 & 1;
    int j0 = jt * 256, n0 = nt * 128, k0 = ks * 384;
    int tid = threadIdx.x, wid = tid >> 6, lane = tid & 63;
    int wm = wid >> 1, wn = wid & 1;

    // staging source offsets (bf16 elements); swizzle baked into source column
    int o16a0 = wid * 128 + lane, o16a1 = o16a0 + 64;
    int ra0 = o16a0 >> 2, ra1 = o16a1 >> 2;
    int qa0 = (o16a0 & 3) ^ ((ra0 >> 1) & 3), qa1 = (o16a1 & 3) ^ ((ra1 >> 1) & 3);
    size_t aoff0 = (size_t)(j0 + ra0) * CC + qa0 * 8 + k0;
    size_t aoff1 = (size_t)(j0 + ra1) * CC + qa1 * 8 + k0;
    int o16b = wid * 64 + lane;
    int rb = o16b >> 2;
    int rbg = n0 + rb; if (rbg > NSP - 1) rbg = NSP - 1;   // clamp (dupes discarded)
    int qb = (o16b & 3) ^ ((rb >> 1) & 3);
    size_t boff = ((size_t)b * NSP + rbg) * CC + qb * 8 + k0;

    char* dA0h = (char*)Ah + (wid * 2 + 0) * 1024;
    char* dA1h = (char*)Ah + (wid * 2 + 1) * 1024;
    char* dA0l = (char*)Al + (wid * 2 + 0) * 1024;
    char* dA1l = (char*)Al + (wid * 2 + 1) * 1024;
    char* dBh  = (char*)Bh + wid * 1024;
    char* dBl  = (char*)Bl + wid * 1024;

    f32x4 acc[4][4];
#pragma unroll
    for (int i = 0; i < 4; i++)
#pragma unroll
        for (int u = 0; u < 4; u++) acc[i][u] = (f32x4){0.f, 0.f, 0.f, 0.f};

    int fr = lane & 15, fq = lane >> 4;
    for (int s = 0; s < 12; ++s) {
        int c0 = s * 32;
        gload16(Whi + aoff0 + c0, dA0h);
        gload16(Whi + aoff1 + c0, dA1h);
        gload16(Wlo + aoff0 + c0, dA0l);
        gload16(Wlo + aoff1 + c0, dA1l);
        gload16(xth + boff + c0, dBh);
        gload16(xtl + boff + c0, dBl);
        __syncthreads();   // drains vmcnt -> LDS tiles ready
        bf16x8 ah[4], al[4];
#pragma unroll
        for (int mi = 0; mi < 4; mi++) {
            int rr = wm * 64 + mi * 16 + fr;
            int e = rr * 32 + ((fq ^ ((rr >> 1) & 3)) << 3);
            ah[mi] = *(const bf16x8*)&Ah[e];
            al[mi] = *(const bf16x8*)&Al[e];
        }
#pragma unroll
        for (int ni = 0; ni < 4; ni++) {
            int rr = wn * 64 + ni * 16 + fr;
            int e = rr * 32 + ((fq ^ ((rr >> 1) & 3)) << 3);
            bf16x8 bh = *(const bf16x8*)&Bh[e];
            bf16x8 bl = *(const bf16x8*)&Bl[e];
#pragma unroll
            for (int mi = 0; mi < 4; mi++) {
                acc[mi][ni] = __builtin_amdgcn_mfma_f32_16x16x32_bf16(ah[mi], bh, acc[mi][ni], 0, 0, 0);
                acc[mi][ni] = __builtin_amdgcn_mfma_f32_16x16x32_bf16(ah[mi], bl, acc[mi][ni], 0, 0, 0);
                acc[mi][ni] = __builtin_amdgcn_mfma_f32_16x16x32_bf16(al[mi], bh, acc[mi][ni], 0, 0, 0);
            }
        }
        __syncthreads();
    }

    // epilogue: bias(ks==0) + rope + q-dot + reduce + guarded atomic
    // C/D: col = lane&15 (n), row = fq*4 + reg (j). RoPE/q-dot are linear -> K-split composes.
#pragma unroll
    for (int mi = 0; mi < 4; mi++) {
        int jf = j0 + wm * 64 + mi * 16;      // 16 | 96 -> frag never straddles a head
        int h = jf / HD;
        float* sdst = sbuf + (size_t)(b * NH + h) * NT;
        int jl = jf + fq * 4;
        float4 qv4 = *(const float4*)&qcls[(size_t)b * EE + jl];
        float4 bi4 = {0.f, 0.f, 0.f, 0.f};
        if (ks == 0) bi4 = *(const float4*)&qkv_b[EE + jl];
        int fi = (jl % HD) >> 1;
#pragma unroll
        for (int ni = 0; ni < 4; ni++) {
            int n = n0 + wn * 64 + ni * 16 + fr;
            int nc = n < NSP ? n : NSP - 1;
            float2 cv = *(const float2*)&ct[nc * 48 + fi];
            float2 sv = *(const float2*)&st[nc * 48 + fi];
            f32x4 a = acc[mi][ni];
            float e0 = a[0] + bi4.x, e1 = a[1] + bi4.y;
            float e2 = a[2] + bi4.z, e3 = a[3] + bi4.w;
            float sc = qv4.x * (e0 * cv.x - e1 * sv.x) + qv4.y * (e1 * cv.x + e0 * sv.x)
                     + qv4.z * (e2 * cv.y - e3 * sv.y) + qv4.w * (e3 * cv.y + e2 * sv.y);
            sc += __shfl_xor(sc, 16);
            sc += __shfl_xor(sc, 32);
            if (lane < 16 && n < NSP) unsafeAtomicAdd(sdst + n + 1, sc);
        }
    }
}

// ---------------- softmax over 577 scores -> p ----------------
__global__ void ksoftmax(const float* __restrict__ sbuf, const float* __restrict__ qcls,
                         const float* __restrict__ kcls, float* __restrict__ p) {
    int bh = blockIdx.x, b = bh >> 3, h = bh & 7;
    int tid = threadIdx.x;
    __shared__ float sm[NT];
    __shared__ float red[4];
    float c0 = 0.f;
    if (tid < HD) c0 = qcls[b * EE + h * HD + tid] * kcls[b * EE + h * HD + tid];
    for (int o = 32; o; o >>= 1) c0 += __shfl_xor(c0, o);
    if ((tid & 63) == 0) red[tid >> 6] = c0;
    __syncthreads();
    float s0 = red[0] + red[1] + red[2] + red[3];
    const float scale = 0.10206207261596575f;   // 96^-0.5
    for (int n = tid; n < NT; n += 256)
        sm[n] = (n == 0 ? s0 : sbuf[(size_t)bh * NT + n]) * scale;
    __syncthreads();
    float m = -1e30f;
    for (int n = tid; n < NT; n += 256) m = fmaxf(m, sm[n]);
    for (int o = 32; o; o >>= 1) m = fmaxf(m, __shfl_xor(m, o));
    __syncthreads();
    if ((tid & 63) == 0) red[tid >> 6] = m;
    __syncthreads();
    m = fmaxf(fmaxf(red[0], red[1]), fmaxf(red[2], red[3]));
    float lsum = 0.f;
    for (int n = tid; n < NT; n += 256) {
        float e = expf(sm[n] - m);
        sm[n] = e;
        lsum += e;
    }
    for (int o = 32; o; o >>= 1) lsum += __shfl_xor(lsum, o);
    __syncthreads();
    if ((tid & 63) == 0) red[tid >> 6] = lsum;
    __syncthreads();
    float inv = 1.0f / (red[0] + red[1] + red[2] + red[3]);
    for (int n = tid; n < NT; n += 256) p[(size_t)bh * NT + n] = sm[n] * inv;
}

// ---------------- weighted token sum: w[b][h][c] = sum_n p[n] t[n][c] ----------------
__global__ void kwsum(const float* __restrict__ x, const float* __restrict__ msum,
                      const float* __restrict__ p, float* __restrict__ w) {
    __shared__ float ps[NH][NT];
    int b = blockIdx.y;
    int tid = threadIdx.x;
    for (int i = tid; i < NH * NT; i += 256)
        ps[i / NT][i % NT] = p[(size_t)b * NH * NT + i];
    __syncthreads();
    int wave = tid >> 6, lane = tid & 63;
    int c = blockIdx.x * 4 + wave;
    const float* xr = x + ((size_t)b * CC + c) * NSP;
    float acc[NH];
#pragma unroll
    for (int h = 0; h < NH; h++) acc[h] = 0.f;
    for (int n = lane; n < NSP; n += 64) {
        float xv = xr[n];
#pragma unroll
        for (int h = 0; h < NH; h++) acc[h] += ps[h][n + 1] * xv;
    }
#pragma unroll
    for (int h = 0; h < NH; h++)
        for (int o = 32; o; o >>= 1) acc[h] += __shfl_xor(acc[h], o);
    if (lane == 0) {
        float mv = msum[(size_t)b * CC + c] * (1.0f / 576.0f);
#pragma unroll
        for (int h = 0; h < NH; h++)
            w[((size_t)(b * NH + h)) * CC + c] = acc[h] + ps[h][0] * mv;
    }
}

// ---------------- o[b][j] = Wv[j,:] . w[b][j/96] + bv[j] ----------------
__global__ void kvproj(const float* __restrict__ qkv_w, const float* __restrict__ qkv_b,
                       const float* __restrict__ w, float* __restrict__ o) {
    int b = blockIdx.y;
    int wave = threadIdx.x >> 6, lane = threadIdx.x & 63;
    int jbase = blockIdx.x * 256 + wave * 64;
    for (int jj = 0; jj < 64; jj++) {
        int j = jbase + jj;
        int h = j / HD;
        const float* wr = qkv_w + (size_t)(2 * EE + j) * CC;
        const float* wv = w + (size_t)(b * NH + h) * CC;
        float s = 0.f;
#pragma unroll
        for (int k = 0; k < 12; k++) s += wr[lane + 64 * k] * wv[lane + 64 * k];
        for (int oo = 32; oo; oo >>= 1) s += __shfl_xor(s, oo);
        if (lane == 0) o[b * EE + j] = s + qkv_b[2 * EE + j];
    }
}

// ---------------- out[b][e] = proj_w[e,:] . o[b] + proj_b[e] ----------------
__global__ void kproj(const float* __restrict__ proj_w, const float* __restrict__ proj_b,
                      const float* __restrict__ o, float* __restrict__ out) {
    int b = blockIdx.y;
    int wave = threadIdx.x >> 6, lane = threadIdx.x & 63;
    int jbase = blockIdx.x * 256 + wave * 64;
    const float* ob = o + b * EE;
    float ov[12];
#pragma unroll
    for (int k = 0; k < 12; k++) ov[k] = ob[lane + 64 * k];
    for (int jj = 0; jj < 64; jj++) {
        int j = jbase + jj;
        const float* wr = proj_w + (size_t)j * CC;
        float s = 0.f;
#pragma unroll
        for (int k = 0; k < 12; k++) s += wr[lane + 64 * k] * ov[k];
        for (int oo = 32; oo; oo >>= 1) s += __shfl_xor(s, oo);
        if (lane == 0) out[b * EE + j] = s + proj_b[j];
    }
}

extern "C" void kernel_launch(void* const* d_in, const int* in_sizes, int n_in,
                              void* d_out, int out_size, void* d_ws, size_t ws_size,
                              hipStream_t stream) {
    (void)in_sizes; (void)n_in; (void)out_size; (void)ws_size;
    const float* x      = (const float*)d_in[0];
    const float* qkv_w  = (const float*)d_in[1];
    const float* qkv_b  = (const float*)d_in[2];
    const float* proj_w = (const float*)d_in[3];
    const float* proj_b = (const float*)d_in[4];
    float* out = (float*)d_out;
    float* ws = (float*)d_ws;

    // NOTE: local names must NOT shadow kernel symbols (round-3 compile bug).
    float* sbuf = ws;                        // 147712
    float* msB  = ws + 147712;               // 24576 raw mean sums (memset with sbuf)
    float* pbuf = ws + 172288;               // 147712
    float* qcb  = ws + 320000;               // 24576
    float* kcb  = ws + 344576;               // 24576
    float* ctb  = ws + 369152;               // 27648
    float* stb  = ws + 396800;               // 27648
    float* wbuf = ws + 424448;               // 196608
    float* obuf = ws + 621056;               // 24576
    __bf16* Whi = (__bf16*)(ws + 645632);    // 589824 bf16 = 294912 f
    __bf16* Wlo = (__bf16*)(ws + 940544);    // 294912 f
    __bf16* xth = (__bf16*)(ws + 1235456);   // 32*576*768 bf16 = 7077888 f
    __bf16* xtl = (__bf16*)(ws + 8313344);   // 7077888 f  (total ~61.6 MB)

    (void)hipMemsetAsync(sbuf, 0, 172288 * sizeof(float), stream);  // sbuf + msB
    ktrig<<<108, 256, 0, stream>>>(ctb, stb);
    kconvw<<<576, 256, 0, stream>>>(qkv_w, Whi, Wlo);
    kconvx<<<dim3(12, 9, 32), 256, 0, stream>>>(x, msB, xth, xtl);
    kcls<<<dim3(96, 2), 256, 0, stream>>>(qkv_w, qkv_b, msB, qcb, kcb);
    kgemm_score<<<960, 512, 0, stream>>>(Whi, Wlo, xth, xtl, qkv_b, ctb, stb, qcb, sbuf);
    ksoftmax<<<256, 256, 0, stream>>>(sbuf, qcb, kcb, pbuf);
    kwsum<<<dim3(192, 32), 256, 0, stream>>>(x, msB, pbuf, wbuf);
    kvproj<<<dim3(3, 32), 256, 0, stream>>>(qkv_w, qkv_b, wbuf, obuf);
    kproj<<<dim3(3, 32), 256, 0, stream>>>(proj_w, proj_b, obuf, out);
}

// Round 10
// 269.829 us; speedup vs baseline: 2.1130x; 1.3024x over previous
//
#include <hip/hip_runtime.h>
#include <math.h>

#define CC 768
#define WWD 24
#define NSP 576     // spatial tokens
#define NT 577      // + CLS
#define EE 768
#define NH 8
#define HD 96

typedef float f32x4 __attribute__((ext_vector_type(4)));
typedef __bf16 bf16x8 __attribute__((ext_vector_type(8)));
typedef __bf16 bf16x4 __attribute__((ext_vector_type(4)));

__device__ __forceinline__ void gload16(const void* g, void* l) {
    __builtin_amdgcn_global_load_lds((const __attribute__((address_space(1))) void*)g,
                                     (__attribute__((address_space(3))) void*)l, 16, 0, 0);
}

// ---------------- kprep: fused Wk->bf16 split (blocks 0..575) + trig tables (576..683) ----
__global__ __launch_bounds__(256) void kprep(const float* __restrict__ qkv_w,
                                             __bf16* __restrict__ Whi, __bf16* __restrict__ Wlo,
                                             float* __restrict__ ct, float* __restrict__ st) {
    int bid = blockIdx.x;
    if (bid < 576) {
        size_t i = ((size_t)bid * 256 + threadIdx.x) * 4;
        const float* Wk = qkv_w + (size_t)EE * CC;
        float4 v = *(const float4*)&Wk[i];
        float vv[4] = {v.x, v.y, v.z, v.w};
        bf16x4 h, l;
#pragma unroll
        for (int k = 0; k < 4; k++) {
            __bf16 hb = (__bf16)vv[k];
            h[k] = hb;
            l[k] = (__bf16)(vv[k] - (float)hb);
        }
        *(bf16x4*)&Whi[i] = h;
        *(bf16x4*)&Wlo[i] = l;
    } else {
        int idx = (bid - 576) * 256 + threadIdx.x;   // 27648 = 108*256
        int n = idx / 48, i = idx % 48;
        int r = n / WWD, c = n % WWD;
        float coord = (i < 24) ? (-1.f + 2.f * (float)r / 23.f)
                               : (-1.f + 2.f * (float)c / 23.f);
        float band = exp2f((float)(i % 24) * (3.0f / 23.0f));
        float e = coord * 3.14159265358979323846f * band;
        ct[idx] = cosf(e);
        st[idx] = sinf(e);
    }
}

// ---------------- transpose+convert x[b] [C][N] f32 -> xt_hi/lo [b][N][C] bf16; fused mean ----
// grid (12, 9, 32) block 256: 64c x 64n tiles
__global__ __launch_bounds__(256) void kconvx(const float* __restrict__ x,
                                              float* __restrict__ msum,
                                              __bf16* __restrict__ xth,
                                              __bf16* __restrict__ xtl) {
    __shared__ float t[64][65];
    int b = blockIdx.z, ct0 = blockIdx.x * 64, nt0 = blockIdx.y * 64;
    int tid = threadIdx.x, lane = tid & 63;
#pragma unroll
    for (int it = 0; it < 4; ++it) {
        int cr = it * 16 + (tid >> 4);
        int ng = (tid & 15) * 4;
        float4 v = *(const float4*)&x[((size_t)b * CC + ct0 + cr) * NSP + nt0 + ng];
        t[cr][ng] = v.x; t[cr][ng + 1] = v.y; t[cr][ng + 2] = v.z; t[cr][ng + 3] = v.w;
        float ps = v.x + v.y + v.z + v.w;
        ps += __shfl_xor(ps, 1); ps += __shfl_xor(ps, 2);
        ps += __shfl_xor(ps, 4); ps += __shfl_xor(ps, 8);
        if ((lane & 15) == 0) unsafeAtomicAdd(&msum[(size_t)b * CC + ct0 + cr], ps);
    }
    __syncthreads();
#pragma unroll
    for (int it = 0; it < 2; ++it) {
        int nr = it * 32 + (tid >> 3);
        int cg = (tid & 7) * 8;
        float v[8];
#pragma unroll
        for (int k = 0; k < 8; k++) v[k] = t[cg + k][nr];
        bf16x8 h, l;
#pragma unroll
        for (int k = 0; k < 8; k++) {
            __bf16 hb = (__bf16)v[k];
            h[k] = hb;
            l[k] = (__bf16)(v[k] - (float)hb);
        }
        size_t o = ((size_t)b * NSP + nt0 + nr) * CC + ct0 + cg;
        *(bf16x8*)&xth[o] = h;
        *(bf16x8*)&xtl[o] = l;
    }
}

// ---------------- CLS q/k: wave-per-j, loop 32 batches (msum L2-hot, 98 KB) ----------------
// grid 384 block 256
__global__ __launch_bounds__(256) void kcls(const float* __restrict__ qkv_w,
                                            const float* __restrict__ qkv_b,
                                            const float* __restrict__ msum,
                                            float* __restrict__ qcls, float* __restrict__ kcls) {
    int wid = threadIdx.x >> 6, lane = threadIdx.x & 63;
    int j = blockIdx.x * 4 + wid;   // 0..1535 (q rows then k rows)
    const float* wr = qkv_w + (size_t)j * CC;
    float wv[12];
#pragma unroll
    for (int k = 0; k < 12; k++) wv[k] = wr[lane + 64 * k];
    float bias = qkv_b[j];
    for (int b = 0; b < 32; b++) {
        const float* mb = msum + (size_t)b * CC;
        float s = 0.f;
#pragma unroll
        for (int k = 0; k < 12; k++) s += wv[k] * mb[lane + 64 * k];
        for (int o = 32; o; o >>= 1) s += __shfl_xor(s, o);
        if (lane == 0) {
            float v = s * (1.0f / 576.0f) + bias;
            if (j < EE) qcls[(size_t)b * EE + j] = v;
            else        kcls[(size_t)b * EE + (j - EE)] = v;
        }
    }
}

// ---------------- main GEMM: split-bf16 MFMA, global_load_lds staging, K-split=2 ----------
// UNCHANGED from round 6 (control). BM=256, BN=128, BK=32, 8 waves, XOR-swizzled LDS.
__global__ __launch_bounds__(512, 4) void kgemm_score(
        const __bf16* __restrict__ Whi, const __bf16* __restrict__ Wlo,
        const __bf16* __restrict__ xth, const __bf16* __restrict__ xtl,
        const float* __restrict__ qkv_b, const float* __restrict__ ct,
        const float* __restrict__ st, const float* __restrict__ qcls,
        float* __restrict__ sbuf) {
    __shared__ __bf16 Ah[256 * 32], Al[256 * 32], Bh[128 * 32], Bl[128 * 32];  // 48 KB
    int id = blockIdx.x;
    int xcd = id & 7, within = id >> 3;
    int bq = within / 30, t = within % 30;
    int b = bq * 8 + xcd;
    int jt = t / 10, r2 = t % 10, nt = r2 >> 1, ks = r2 & 1;
    int j0 = jt * 256, n0 = nt * 128, k0 = ks * 384;
    int tid = threadIdx.x, wid = tid >> 6, lane = tid & 63;
    int wm = wid >> 1, wn = wid & 1;

    int o16a0 = wid * 128 + lane, o16a1 = o16a0 + 64;
    int ra0 = o16a0 >> 2, ra1 = o16a1 >> 2;
    int qa0 = (o16a0 & 3) ^ ((ra0 >> 1) & 3), qa1 = (o16a1 & 3) ^ ((ra1 >> 1) & 3);
    size_t aoff0 = (size_t)(j0 + ra0) * CC + qa0 * 8 + k0;
    size_t aoff1 = (size_t)(j0 + ra1) * CC + qa1 * 8 + k0;
    int o16b = wid * 64 + lane;
    int rb = o16b >> 2;
    int rbg = n0 + rb; if (rbg > NSP - 1) rbg = NSP - 1;
    int qb = (o16b & 3) ^ ((rb >> 1) & 3);
    size_t boff = ((size_t)b * NSP + rbg) * CC + qb * 8 + k0;

    char* dA0h = (char*)Ah + (wid * 2 + 0) * 1024;
    char* dA1h = (char*)Ah + (wid * 2 + 1) * 1024;
    char* dA0l = (char*)Al + (wid * 2 + 0) * 1024;
    char* dA1l = (char*)Al + (wid * 2 + 1) * 1024;
    char* dBh  = (char*)Bh + wid * 1024;
    char* dBl  = (char*)Bl + wid * 1024;

    f32x4 acc[4][4];
#pragma unroll
    for (int i = 0; i < 4; i++)
#pragma unroll
        for (int u = 0; u < 4; u++) acc[i][u] = (f32x4){0.f, 0.f, 0.f, 0.f};

    int fr = lane & 15, fq = lane >> 4;
    for (int s = 0; s < 12; ++s) {
        int c0 = s * 32;
        gload16(Whi + aoff0 + c0, dA0h);
        gload16(Whi + aoff1 + c0, dA1h);
        gload16(Wlo + aoff0 + c0, dA0l);
        gload16(Wlo + aoff1 + c0, dA1l);
        gload16(xth + boff + c0, dBh);
        gload16(xtl + boff + c0, dBl);
        __syncthreads();
        bf16x8 ah[4], al[4];
#pragma unroll
        for (int mi = 0; mi < 4; mi++) {
            int rr = wm * 64 + mi * 16 + fr;
            int e = rr * 32 + ((fq ^ ((rr >> 1) & 3)) << 3);
            ah[mi] = *(const bf16x8*)&Ah[e];
            al[mi] = *(const bf16x8*)&Al[e];
        }
#pragma unroll
        for (int ni = 0; ni < 4; ni++) {
            int rr = wn * 64 + ni * 16 + fr;
            int e = rr * 32 + ((fq ^ ((rr >> 1) & 3)) << 3);
            bf16x8 bh = *(const bf16x8*)&Bh[e];
            bf16x8 bl = *(const bf16x8*)&Bl[e];
#pragma unroll
            for (int mi = 0; mi < 4; mi++) {
                acc[mi][ni] = __builtin_amdgcn_mfma_f32_16x16x32_bf16(ah[mi], bh, acc[mi][ni], 0, 0, 0);
                acc[mi][ni] = __builtin_amdgcn_mfma_f32_16x16x32_bf16(ah[mi], bl, acc[mi][ni], 0, 0, 0);
                acc[mi][ni] = __builtin_amdgcn_mfma_f32_16x16x32_bf16(al[mi], bh, acc[mi][ni], 0, 0, 0);
            }
        }
        __syncthreads();
    }

#pragma unroll
    for (int mi = 0; mi < 4; mi++) {
        int jf = j0 + wm * 64 + mi * 16;
        int h = jf / HD;
        float* sdst = sbuf + (size_t)(b * NH + h) * NT;
        int jl = jf + fq * 4;
        float4 qv4 = *(const float4*)&qcls[(size_t)b * EE + jl];
        float4 bi4 = {0.f, 0.f, 0.f, 0.f};
        if (ks == 0) bi4 = *(const float4*)&qkv_b[EE + jl];
        int fi = (jl % HD) >> 1;
#pragma unroll
        for (int ni = 0; ni < 4; ni++) {
            int n = n0 + wn * 64 + ni * 16 + fr;
            int nc = n < NSP ? n : NSP - 1;
            float2 cv = *(const float2*)&ct[nc * 48 + fi];
            float2 sv = *(const float2*)&st[nc * 48 + fi];
            f32x4 a = acc[mi][ni];
            float e0 = a[0] + bi4.x, e1 = a[1] + bi4.y;
            float e2 = a[2] + bi4.z, e3 = a[3] + bi4.w;
            float sc = qv4.x * (e0 * cv.x - e1 * sv.x) + qv4.y * (e1 * cv.x + e0 * sv.x)
                     + qv4.z * (e2 * cv.y - e3 * sv.y) + qv4.w * (e3 * cv.y + e2 * sv.y);
            sc += __shfl_xor(sc, 16);
            sc += __shfl_xor(sc, 32);
            if (lane < 16 && n < NSP) unsafeAtomicAdd(sdst + n + 1, sc);
        }
    }
}

// ---------------- fused softmax + weighted token sum ----------------
// grid (192, 32) block 256. Each block: per-batch softmax (redundant, ~3 us chip-wide)
// into LDS, then 4 waves x 1 c-row weighted sum. Eliminates ksoftmax launch + pbuf.
__global__ __launch_bounds__(256) void kwsum(const float* __restrict__ x,
                                             const float* __restrict__ msum,
                                             const float* __restrict__ sbuf,
                                             const float* __restrict__ qcls,
                                             const float* __restrict__ kcls,
                                             float* __restrict__ w) {
    __shared__ float ps[NH][NT];
    int b = blockIdx.y;
    int tid = threadIdx.x, wave = tid >> 6, lane = tid & 63;
    const float scale = 0.10206207261596575f;   // 96^-0.5
#pragma unroll
    for (int hh = 0; hh < 2; hh++) {
        int h = wave * 2 + hh;
        // CLS score (q.k over 96)
        float c0 = 0.f;
        if (lane < 48) {
            int i0 = b * EE + h * HD + lane;
            c0 = qcls[i0] * kcls[i0] + qcls[i0 + 48] * kcls[i0 + 48];
        }
        for (int o = 32; o; o >>= 1) c0 += __shfl_xor(c0, o);
        const float* srow = sbuf + (size_t)(b * NH + h) * NT;
        float vals[10];
        float m = -1e30f;
#pragma unroll
        for (int i = 0; i < 10; i++) {
            int n = lane + i * 64;
            float v = -1e30f;
            if (n < NT) v = (n == 0 ? c0 : srow[n]) * scale;
            vals[i] = v;
            m = fmaxf(m, v);
        }
        for (int o = 32; o; o >>= 1) m = fmaxf(m, __shfl_xor(m, o));
        float lsum = 0.f;
#pragma unroll
        for (int i = 0; i < 10; i++) {
            int n = lane + i * 64;
            if (n < NT) {
                float e = expf(vals[i] - m);
                ps[h][n] = e;
                lsum += e;
            }
        }
        for (int o = 32; o; o >>= 1) lsum += __shfl_xor(lsum, o);
        float inv = 1.0f / lsum;
#pragma unroll
        for (int i = 0; i < 10; i++) {
            int n = lane + i * 64;
            if (n < NT) ps[h][n] *= inv;
        }
    }
    __syncthreads();
    int c = blockIdx.x * 4 + wave;
    const float* xr = x + ((size_t)b * CC + c) * NSP;
    float acc[NH];
#pragma unroll
    for (int h = 0; h < NH; h++) acc[h] = 0.f;
    for (int n = lane; n < NSP; n += 64) {
        float xv = xr[n];
#pragma unroll
        for (int h = 0; h < NH; h++) acc[h] += ps[h][n + 1] * xv;
    }
#pragma unroll
    for (int h = 0; h < NH; h++)
        for (int o = 32; o; o >>= 1) acc[h] += __shfl_xor(acc[h], o);
    if (lane == 0) {
        float mv = msum[(size_t)b * CC + c] * (1.0f / 576.0f);
#pragma unroll
        for (int h = 0; h < NH; h++)
            w[((size_t)(b * NH + h)) * CC + c] = acc[h] + ps[h][0] * mv;
    }
}

// ---------------- o[b][j] = Wv[j,:] . w[b][j/96] + bv[j] : wave-per-j ----------------
// grid (192, 32) block 256
__global__ __launch_bounds__(256) void kvproj(const float* __restrict__ qkv_w,
                                              const float* __restrict__ qkv_b,
                                              const float* __restrict__ w,
                                              float* __restrict__ o) {
    int b = blockIdx.y;
    int wid = threadIdx.x >> 6, lane = threadIdx.x & 63;
    int j = blockIdx.x * 4 + wid;   // 0..767
    int h = j / HD;
    const float* wr = qkv_w + (size_t)(2 * EE + j) * CC;
    const float* wv = w + (size_t)(b * NH + h) * CC;
    float s = 0.f;
#pragma unroll
    for (int k = 0; k < 12; k++) s += wr[lane + 64 * k] * wv[lane + 64 * k];
    for (int oo = 32; oo; oo >>= 1) s += __shfl_xor(s, oo);
    if (lane == 0) o[(size_t)b * EE + j] = s + qkv_b[2 * EE + j];
}

// ---------------- out[b][e] = proj_w[e,:] . o[b] + proj_b[e] : wave-per-e ----------------
// grid (192, 32) block 256
__global__ __launch_bounds__(256) void kproj(const float* __restrict__ proj_w,
                                             const float* __restrict__ proj_b,
                                             const float* __restrict__ o,
                                             float* __restrict__ out) {
    int b = blockIdx.y;
    int wid = threadIdx.x >> 6, lane = threadIdx.x & 63;
    int j = blockIdx.x * 4 + wid;   // 0..767
    const float* wr = proj_w + (size_t)j * CC;
    const float* ob = o + (size_t)b * EE;
    float s = 0.f;
#pragma unroll
    for (int k = 0; k < 12; k++) s += wr[lane + 64 * k] * ob[lane + 64 * k];
    for (int oo = 32; oo; oo >>= 1) s += __shfl_xor(s, oo);
    if (lane == 0) out[(size_t)b * EE + j] = s + proj_b[j];
}

extern "C" void kernel_launch(void* const* d_in, const int* in_sizes, int n_in,
                              void* d_out, int out_size, void* d_ws, size_t ws_size,
                              hipStream_t stream) {
    (void)in_sizes; (void)n_in; (void)out_size; (void)ws_size;
    const float* x      = (const float*)d_in[0];
    const float* qkv_w  = (const float*)d_in[1];
    const float* qkv_b  = (const float*)d_in[2];
    const float* proj_w = (const float*)d_in[3];
    const float* proj_b = (const float*)d_in[4];
    float* out = (float*)d_out;
    float* ws = (float*)d_ws;

    // NOTE: local names must NOT shadow kernel symbols (round-3 compile bug).
    float* sbuf = ws;                        // 147712
    float* msB  = ws + 147712;               // 24576 raw mean sums (memset with sbuf)
    float* qcb  = ws + 320000;               // 24576
    float* kcb  = ws + 344576;               // 24576
    float* ctb  = ws + 369152;               // 27648
    float* stb  = ws + 396800;               // 27648
    float* wbuf = ws + 424448;               // 196608
    float* obuf = ws + 621056;               // 24576
    __bf16* Whi = (__bf16*)(ws + 645632);    // 294912 f
    __bf16* Wlo = (__bf16*)(ws + 940544);    // 294912 f
    __bf16* xth = (__bf16*)(ws + 1235456);   // 7077888 f
    __bf16* xtl = (__bf16*)(ws + 8313344);   // 7077888 f  (total ~61.6 MB)

    (void)hipMemsetAsync(sbuf, 0, 172288 * sizeof(float), stream);  // sbuf + msB
    kprep<<<684, 256, 0, stream>>>(qkv_w, Whi, Wlo, ctb, stb);
    kconvx<<<dim3(12, 9, 32), 256, 0, stream>>>(x, msB, xth, xtl);
    kcls<<<384, 256, 0, stream>>>(qkv_w, qkv_b, msB, qcb, kcb);
    kgemm_score<<<960, 512, 0, stream>>>(Whi, Wlo, xth, xtl, qkv_b, ctb, stb, qcb, sbuf);
    kwsum<<<dim3(192, 32), 256, 0, stream>>>(x, msB, sbuf, qcb, kcb, wbuf);
    kvproj<<<dim3(192, 32), 256, 0, stream>>>(qkv_w, qkv_b, wbuf, obuf);
    kproj<<<dim3(192, 32), 256, 0, stream>>>(proj_w, proj_b, obuf, out);
}